// Round 1
// baseline (321.974 us; speedup 1.0000x reference)
//
#include <hip/hip_runtime.h>
#include <cstdint>
#include <cstddef>

#define NB 4
#define CH 256
#define SS 4096
#define EE 128
#define QSCALE 0.08838834764831845f /* 1/sqrt(128) */

typedef __attribute__((ext_vector_type(8))) short bfrag;          // 8 bf16 = 4 VGPR
typedef __attribute__((ext_vector_type(8))) unsigned short u16x8; // 16B store
typedef __attribute__((ext_vector_type(4))) float f32x4;          // MFMA acc

__device__ __forceinline__ unsigned short f2bf(float f) {
  union { float f; unsigned int u; } v; v.f = f;
  unsigned int u = v.u;
  unsigned int r = u + 0x7FFFu + ((u >> 16) & 1u);  // RNE
  return (unsigned short)(r >> 16);
}

// ---------------------------------------------------------------------------
// Pass 0: fused fp32 -> bf16 conversion of x + the three weight matrices
// ---------------------------------------------------------------------------
__global__ __launch_bounds__(256) void cvt_all(
    const float* __restrict__ x,   const float* __restrict__ thw,
    const float* __restrict__ phw, const float* __restrict__ pw,
    unsigned short* __restrict__ xb,   unsigned short* __restrict__ thwb,
    unsigned short* __restrict__ phwb, unsigned short* __restrict__ pwb)
{
  const int nx4 = NB * CH * SS / 4;
  const int nw4 = EE * CH / 4;
  const int np4 = CH * CH / 4;
  int i = blockIdx.x * 256 + threadIdx.x;
  const float* src; unsigned short* dst; int off;
  if      (i < nx4)                 { src = x;   dst = xb;   off = i; }
  else if (i < nx4 + nw4)           { src = thw; dst = thwb; off = i - nx4; }
  else if (i < nx4 + 2 * nw4)       { src = phw; dst = phwb; off = i - nx4 - nw4; }
  else if (i < nx4 + 2 * nw4 + np4) { src = pw;  dst = pwb;  off = i - nx4 - 2 * nw4; }
  else return;
  float4 v = reinterpret_cast<const float4*>(src)[off];
  ushort4 o;
  o.x = f2bf(v.x); o.y = f2bf(v.y); o.z = f2bf(v.z); o.w = f2bf(v.w);
  reinterpret_cast<ushort4*>(dst)[off] = o;
}

// ---------------------------------------------------------------------------
// Pass 1: z=0: Qt[n][s][e] = QSCALE * sum_c theta_w[e][c] * x[n][c][s]
//         z=1: Kt[n][s][e] =          sum_c phi_w[e][c]   * x[n][c][s]
// Grid (SS/64, NB, 2): 512 blocks -> 2 blocks/CU.
// ---------------------------------------------------------------------------
__global__ __launch_bounds__(256) void pass1_qk(
    const unsigned short* __restrict__ xb,
    const unsigned short* __restrict__ thw,
    const unsigned short* __restrict__ phw,
    unsigned short* __restrict__ Qt,
    unsigned short* __restrict__ Kt)
{
  __shared__ unsigned short xT[64][CH + 8];
  const int t  = threadIdx.x;
  const int n  = blockIdx.y;
  const int s0 = blockIdx.x * 64;
  const int z  = blockIdx.z;

  // stage x^T tile: coalesced reads along s, transposed writes into LDS
  {
    const int soff = (t & 15) * 4;
    const int c0   = t >> 4;
    const ushort4* xv = reinterpret_cast<const ushort4*>(
        xb + ((size_t)n * CH) * SS + s0);
    #pragma unroll
    for (int ci = 0; ci < 16; ++ci) {
      const int c = c0 + ci * 16;
      ushort4 v = xv[c * (SS / 4) + (soff >> 2)];
      xT[soff + 0][c] = v.x;
      xT[soff + 1][c] = v.y;
      xT[soff + 2][c] = v.z;
      xT[soff + 3][c] = v.w;
    }
  }
  __syncthreads();

  const int w    = t >> 6;
  const int lane = t & 63;
  const int q    = lane >> 4;
  const int mr   = lane & 15;

  bfrag a[8];
  {
    const bfrag* rp = reinterpret_cast<const bfrag*>(&xT[w * 16 + mr][0]);
    #pragma unroll
    for (int k = 0; k < 8; ++k) a[k] = rp[k * 4 + q];
  }

  const unsigned short* wsel = z ? phw : thw;
  unsigned short*       osel = z ? Kt  : Qt;
  const float           sc   = z ? 1.0f : QSCALE;
  const bfrag* wp = reinterpret_cast<const bfrag*>(wsel);
  #pragma unroll
  for (int nt = 0; nt < 8; ++nt) {
    f32x4 acc = {0.f, 0.f, 0.f, 0.f};
    #pragma unroll
    for (int k = 0; k < 8; ++k) {
      bfrag b = wp[(nt * 16 + mr) * (CH / 8) + k * 4 + q];
      acc = __builtin_amdgcn_mfma_f32_16x16x32_bf16(a[k], b, acc, 0, 0, 0);
    }
    #pragma unroll
    for (int i = 0; i < 4; ++i) {
      const int srow = s0 + w * 16 + q * 4 + i;
      osel[((size_t)n * SS + srow) * EE + nt * 16 + mr] = f2bf(acc[i] * sc);
    }
  }
}

// ---------------------------------------------------------------------------
// Pass 2: flash attention. 512 threads (8 waves), Q-tile 32, key tiles 128.
// Grid: 512 blocks (1D) -> 2 blocks/CU so one block's softmax (VALU) overlaps
// the other's QK/PV (MFMA). XCD-aware swizzle: block id -> XCD id&7 (HW
// round-robin heuristic); n = xcd>>1 pins each batch image to 2 XCDs so the
// per-XCD K+V working set (3 MB) stays L2-resident despite 2x tile traffic.
// Wave w: QK^T key cols w*16..w*16+15; PV output cols w*32..w*32+31.
// ---------------------------------------------------------------------------
__global__ __launch_bounds__(512, 4) void pass2_attn(
    const unsigned short* __restrict__ Qt,
    const unsigned short* __restrict__ Kt,
    const unsigned short* __restrict__ xb,
    unsigned short* __restrict__ Yt)
{
  __shared__ float          S_lds[32][132];   // row stride 132 dw: 2-way on MFMA write
  __shared__ unsigned short P_lds[32][136];   // 16B-aligned rows
  __shared__ float row_m[32], row_l[32], row_alpha[32];

  const int t    = threadIdx.x;
  const int id   = blockIdx.x;
  const int xcd  = id & 7;                    // HW round-robin XCD of this block
  const int n    = xcd >> 1;                  // 2 XCDs per batch image
  const int s0   = ((id >> 3) * 2 + (xcd & 1)) * 32;  // bijective over 128 tiles/n
  const int w    = t >> 6;      // 0..7
  const int lane = t & 63;
  const int q    = lane >> 4;
  const int mr   = lane & 15;

  if (t < 32) { row_m[t] = -INFINITY; row_l[t] = 0.f; }

  // Q fragments (32 rows x 128 e) in registers for the whole loop
  bfrag qa[2][4];
  #pragma unroll
  for (int ms = 0; ms < 2; ++ms) {
    const bfrag* rp = reinterpret_cast<const bfrag*>(
        Qt + ((size_t)n * SS + s0 + ms * 16 + mr) * EE);
    #pragma unroll
    for (int k = 0; k < 4; ++k) qa[ms][k] = rp[k * 4 + q];
  }

  f32x4 o_acc[2][2];
  #pragma unroll
  for (int ms = 0; ms < 2; ++ms)
    #pragma unroll
    for (int nt = 0; nt < 2; ++nt) o_acc[ms][nt] = (f32x4){0.f, 0.f, 0.f, 0.f};

  // K fragments for iter 0 (wave w -> key col block w)
  bfrag kb[4];
  {
    const bfrag* rp = reinterpret_cast<const bfrag*>(
        Kt + ((size_t)n * SS + w * 16 + mr) * EE);
    #pragma unroll
    for (int k = 0; k < 4; ++k) kb[k] = rp[k * 4 + q];
  }

  for (int t0 = 0; t0 < SS; t0 += 128) {
    // ---- prefetch V fragments for THIS iter (consumed after softmax) ----
    bfrag vb[4][2];
    #pragma unroll
    for (int nt = 0; nt < 2; ++nt) {
      const int c = w * 32 + nt * 16 + mr;
      const bfrag* vp = reinterpret_cast<const bfrag*>(
          xb + ((size_t)n * CH + c) * SS + t0);
      #pragma unroll
      for (int kk = 0; kk < 4; ++kk) vb[kk][nt] = vp[kk * 4 + q];
    }

    // ---- QK^T: wave w -> 16 key cols ----
    #pragma unroll
    for (int ms = 0; ms < 2; ++ms) {
      f32x4 acc = {0.f, 0.f, 0.f, 0.f};
      #pragma unroll
      for (int k = 0; k < 4; ++k)
        acc = __builtin_amdgcn_mfma_f32_16x16x32_bf16(qa[ms][k], kb[k], acc, 0, 0, 0);
      #pragma unroll
      for (int i = 0; i < 4; ++i)
        S_lds[ms * 16 + q * 4 + i][w * 16 + mr] = acc[i];
    }
    __syncthreads();

    // ---- prefetch K fragments for NEXT iter ----
    {
      const int t1 = t0 + 128;
      if (t1 < SS) {
        const bfrag* rp = reinterpret_cast<const bfrag*>(
            Kt + ((size_t)n * SS + t1 + w * 16 + mr) * EE);
        #pragma unroll
        for (int k = 0; k < 4; ++k) kb[k] = rp[k * 4 + q];
      }
    }

    // ---- online softmax: 16 lanes/row, float4 reads, ushort8 P writes ----
    {
      const int r  = t >> 4;        // 0..31
      const int cg = t & 15;        // 16 lane-groups x 8 cols = 128 key cols
      const float4* srow = reinterpret_cast<const float4*>(&S_lds[r][cg * 8]);
      float4 v0 = srow[0], v1 = srow[1];
      float vmax = fmaxf(fmaxf(fmaxf(v0.x, v0.y), fmaxf(v0.z, v0.w)),
                         fmaxf(fmaxf(v1.x, v1.y), fmaxf(v1.z, v1.w)));
      vmax = fmaxf(vmax, __shfl_xor(vmax, 1, 16));
      vmax = fmaxf(vmax, __shfl_xor(vmax, 2, 16));
      vmax = fmaxf(vmax, __shfl_xor(vmax, 4, 16));
      vmax = fmaxf(vmax, __shfl_xor(vmax, 8, 16));
      const float m_old = row_m[r];
      const float m_new = fmaxf(m_old, vmax);

      float p[8];
      p[0]=__expf(v0.x-m_new); p[1]=__expf(v0.y-m_new); p[2]=__expf(v0.z-m_new); p[3]=__expf(v0.w-m_new);
      p[4]=__expf(v1.x-m_new); p[5]=__expf(v1.y-m_new); p[6]=__expf(v1.z-m_new); p[7]=__expf(v1.w-m_new);
      float sum = 0.f;
      u16x8 pk;
      #pragma unroll
      for (int j = 0; j < 8; ++j) { sum += p[j]; pk[j] = f2bf(p[j]); }
      *reinterpret_cast<u16x8*>(&P_lds[r][cg * 8]) = pk;
      sum += __shfl_xor(sum, 1, 16);
      sum += __shfl_xor(sum, 2, 16);
      sum += __shfl_xor(sum, 4, 16);
      sum += __shfl_xor(sum, 8, 16);
      if (cg == 0) {
        const float al = __expf(m_old - m_new);   // exp(-inf)=0 on iter 0
        row_alpha[r] = al;
        row_m[r]     = m_new;
        row_l[r]     = row_l[r] * al + sum;
      }
    }
    __syncthreads();

    // ---- rescale O, then O += P @ V ----
    #pragma unroll
    for (int ms = 0; ms < 2; ++ms) {
      float al[4];
      #pragma unroll
      for (int i = 0; i < 4; ++i) al[i] = row_alpha[ms * 16 + q * 4 + i];
      #pragma unroll
      for (int nt = 0; nt < 2; ++nt)
        #pragma unroll
        for (int i = 0; i < 4; ++i) o_acc[ms][nt][i] *= al[i];
    }

    #pragma unroll
    for (int kk = 0; kk < 4; ++kk) {
      bfrag pa[2];
      #pragma unroll
      for (int ms = 0; ms < 2; ++ms)
        pa[ms] = reinterpret_cast<const bfrag*>(&P_lds[ms * 16 + mr][0])[kk * 4 + q];
      #pragma unroll
      for (int nt = 0; nt < 2; ++nt)
        #pragma unroll
        for (int ms = 0; ms < 2; ++ms)
          o_acc[ms][nt] = __builtin_amdgcn_mfma_f32_16x16x32_bf16(
              pa[ms], vb[kk][nt], o_acc[ms][nt], 0, 0, 0);
    }
  }

  // ---- epilogue ----
  #pragma unroll
  for (int ms = 0; ms < 2; ++ms) {
    float inv[4];
    #pragma unroll
    for (int i = 0; i < 4; ++i) inv[i] = 1.0f / row_l[ms * 16 + q * 4 + i];
    #pragma unroll
    for (int nt = 0; nt < 2; ++nt) {
      const int c = w * 32 + nt * 16 + mr;
      #pragma unroll
      for (int i = 0; i < 4; ++i) {
        const int s = s0 + ms * 16 + q * 4 + i;
        Yt[((size_t)n * SS + s) * CH + c] = f2bf(o_acc[ms][nt][i] * inv[i]);
      }
    }
  }
}

// ---------------------------------------------------------------------------
// Pass 3: out[n][o][s] = x[n][o][s] + sum_c proj_w[o][c] * Yt[n][s][c]
// ---------------------------------------------------------------------------
__global__ __launch_bounds__(256) void pass3_proj(
    const unsigned short* __restrict__ Yt,
    const unsigned short* __restrict__ pw,
    const float* __restrict__ x,
    float* __restrict__ out)
{
  const int t    = threadIdx.x;
  const int w    = t >> 6;
  const int lane = t & 63;
  const int q    = lane >> 4;
  const int mr   = lane & 15;
  const int n    = blockIdx.z;
  const int o0   = blockIdx.y * 64 + w * 16;
  const int s1   = blockIdx.x * 64;

  bfrag a[8];
  {
    const bfrag* ap = reinterpret_cast<const bfrag*>(pw + (o0 + mr) * CH);
    #pragma unroll
    for (int k = 0; k < 8; ++k) a[k] = ap[k * 4 + q];
  }

  #pragma unroll
  for (int nt = 0; nt < 4; ++nt) {
    f32x4 acc = {0.f, 0.f, 0.f, 0.f};
    const bfrag* bp = reinterpret_cast<const bfrag*>(
        Yt + ((size_t)n * SS + s1 + nt * 16 + mr) * CH);
    #pragma unroll
    for (int k = 0; k < 8; ++k)
      acc = __builtin_amdgcn_mfma_f32_16x16x32_bf16(a[k], bp[k * 4 + q], acc, 0, 0, 0);
    #pragma unroll
    for (int i = 0; i < 4; ++i) {
      const int o = o0 + q * 4 + i;
      const int s = s1 + nt * 16 + mr;
      const size_t idx = ((size_t)n * CH + o) * SS + s;
      out[idx] = x[idx] + acc[i];
    }
  }
}

// ---------------------------------------------------------------------------
extern "C" void kernel_launch(void* const* d_in, const int* in_sizes, int n_in,
                              void* d_out, int out_size, void* d_ws, size_t ws_size,
                              hipStream_t stream) {
  const float* x   = (const float*)d_in[0];
  const float* thw = (const float*)d_in[1];
  const float* phw = (const float*)d_in[2];
  const float* pw  = (const float*)d_in[3];
  float* out = (float*)d_out;

  unsigned short* xb   = (unsigned short*)d_ws;               // 8 MB
  unsigned short* Yt   = xb + (size_t)NB * CH * SS;           // 8 MB
  unsigned short* Qt   = Yt + (size_t)NB * CH * SS;           // 4 MB
  unsigned short* Kt   = Qt + (size_t)NB * SS * EE;           // 4 MB
  unsigned short* thwb = Kt + (size_t)NB * SS * EE;           // 64 KB
  unsigned short* phwb = thwb + EE * CH;                      // 64 KB
  unsigned short* pwb  = phwb + EE * CH;                      // 128 KB

  const int nx4 = NB * CH * SS / 4;
  const int nw4 = EE * CH / 4;
  const int np4 = CH * CH / 4;
  const int tot4 = nx4 + 2 * nw4 + np4;
  cvt_all<<<(tot4 + 255) / 256, 256, 0, stream>>>(
      x, thw, phw, pw, xb, thwb, phwb, pwb);

  pass1_qk  <<<dim3(SS / 64, NB, 2),       256, 0, stream>>>(xb, thwb, phwb, Qt, Kt);
  pass2_attn<<<dim3(NB * SS / 32),         512, 0, stream>>>(Qt, Kt, xb, Yt);
  pass3_proj<<<dim3(SS / 64, CH / 64, NB), 256, 0, stream>>>(Yt, pwb, x, out);
}

// Round 2
// 213.758 us; speedup vs baseline: 1.5063x; 1.5063x over previous
//
#include <hip/hip_runtime.h>
#include <cstdint>
#include <cstddef>

#define NB 4
#define CH 256
#define SS 4096
#define EE 128
#define QSCALE 0.08838834764831845f /* 1/sqrt(128) */

typedef __attribute__((ext_vector_type(8))) short bfrag;          // 8 bf16 = 4 VGPR
typedef __attribute__((ext_vector_type(8))) unsigned short u16x8; // 16B store
typedef __attribute__((ext_vector_type(4))) float f32x4;          // MFMA acc

__device__ __forceinline__ unsigned short f2bf(float f) {
  union { float f; unsigned int u; } v; v.f = f;
  unsigned int u = v.u;
  unsigned int r = u + 0x7FFFu + ((u >> 16) & 1u);  // RNE
  return (unsigned short)(r >> 16);
}

// ---------------------------------------------------------------------------
// Pass 0: fused fp32 -> bf16 conversion of x + the three weight matrices
// ---------------------------------------------------------------------------
__global__ __launch_bounds__(256) void cvt_all(
    const float* __restrict__ x,   const float* __restrict__ thw,
    const float* __restrict__ phw, const float* __restrict__ pw,
    unsigned short* __restrict__ xb,   unsigned short* __restrict__ thwb,
    unsigned short* __restrict__ phwb, unsigned short* __restrict__ pwb)
{
  const int nx4 = NB * CH * SS / 4;
  const int nw4 = EE * CH / 4;
  const int np4 = CH * CH / 4;
  int i = blockIdx.x * 256 + threadIdx.x;
  const float* src; unsigned short* dst; int off;
  if      (i < nx4)                 { src = x;   dst = xb;   off = i; }
  else if (i < nx4 + nw4)           { src = thw; dst = thwb; off = i - nx4; }
  else if (i < nx4 + 2 * nw4)       { src = phw; dst = phwb; off = i - nx4 - nw4; }
  else if (i < nx4 + 2 * nw4 + np4) { src = pw;  dst = pwb;  off = i - nx4 - 2 * nw4; }
  else return;
  float4 v = reinterpret_cast<const float4*>(src)[off];
  ushort4 o;
  o.x = f2bf(v.x); o.y = f2bf(v.y); o.z = f2bf(v.z); o.w = f2bf(v.w);
  reinterpret_cast<ushort4*>(dst)[off] = o;
}

// ---------------------------------------------------------------------------
// Pass 1: z=0: Qt[n][s][e] = QSCALE * sum_c theta_w[e][c] * x[n][c][s]
//         z=1: Kt[n][s][e] =          sum_c phi_w[e][c]   * x[n][c][s]
// Grid (SS/64, NB, 2): 512 blocks -> 2 blocks/CU.
// ---------------------------------------------------------------------------
__global__ __launch_bounds__(256) void pass1_qk(
    const unsigned short* __restrict__ xb,
    const unsigned short* __restrict__ thw,
    const unsigned short* __restrict__ phw,
    unsigned short* __restrict__ Qt,
    unsigned short* __restrict__ Kt)
{
  __shared__ unsigned short xT[64][CH + 8];
  const int t  = threadIdx.x;
  const int n  = blockIdx.y;
  const int s0 = blockIdx.x * 64;
  const int z  = blockIdx.z;

  // stage x^T tile: coalesced reads along s, transposed writes into LDS
  {
    const int soff = (t & 15) * 4;
    const int c0   = t >> 4;
    const ushort4* xv = reinterpret_cast<const ushort4*>(
        xb + ((size_t)n * CH) * SS + s0);
    #pragma unroll
    for (int ci = 0; ci < 16; ++ci) {
      const int c = c0 + ci * 16;
      ushort4 v = xv[c * (SS / 4) + (soff >> 2)];
      xT[soff + 0][c] = v.x;
      xT[soff + 1][c] = v.y;
      xT[soff + 2][c] = v.z;
      xT[soff + 3][c] = v.w;
    }
  }
  __syncthreads();

  const int w    = t >> 6;
  const int lane = t & 63;
  const int q    = lane >> 4;
  const int mr   = lane & 15;

  bfrag a[8];
  {
    const bfrag* rp = reinterpret_cast<const bfrag*>(&xT[w * 16 + mr][0]);
    #pragma unroll
    for (int k = 0; k < 8; ++k) a[k] = rp[k * 4 + q];
  }

  const unsigned short* wsel = z ? phw : thw;
  unsigned short*       osel = z ? Kt  : Qt;
  const float           sc   = z ? 1.0f : QSCALE;
  const bfrag* wp = reinterpret_cast<const bfrag*>(wsel);
  #pragma unroll
  for (int nt = 0; nt < 8; ++nt) {
    f32x4 acc = {0.f, 0.f, 0.f, 0.f};
    #pragma unroll
    for (int k = 0; k < 8; ++k) {
      bfrag b = wp[(nt * 16 + mr) * (CH / 8) + k * 4 + q];
      acc = __builtin_amdgcn_mfma_f32_16x16x32_bf16(a[k], b, acc, 0, 0, 0);
    }
    #pragma unroll
    for (int i = 0; i < 4; ++i) {
      const int srow = s0 + w * 16 + q * 4 + i;
      osel[((size_t)n * SS + srow) * EE + nt * 16 + mr] = f2bf(acc[i] * sc);
    }
  }
}

// ---------------------------------------------------------------------------
// Pass 2: flash attention. 512 threads (8 waves), Q-tile 64, key tiles 128.
// Round-0 structure (measured 108.6 us) + ONE change: n-per-XCD-pair block
// swizzle. Each block streams K(1MB)+V(2MB) of its image; without pinning,
// every XCD touches all 4 images (16MB >> 4MiB L2) and K/V stream from L3 at
// the measured ~7.1 TB/s cap. Pinning n = (id&7)>>1 gives each XCD a 3.5MB
// working set, and same-n blocks stream t0 in lockstep -> hot window ~100KB
// stays L2-resident. HW placement model: block id -> XCD (id % 8) (m157/m204).
// Wave w: QK^T key cols w*16..w*16+15; PV output cols w*32..w*32+31.
// ---------------------------------------------------------------------------
__global__ __launch_bounds__(512, 2) void pass2_attn(
    const unsigned short* __restrict__ Qt,
    const unsigned short* __restrict__ Kt,
    const unsigned short* __restrict__ xb,
    unsigned short* __restrict__ Yt)
{
  __shared__ float          S_lds[64][132];   // row stride 132 dw: 2-way on MFMA write
  __shared__ unsigned short P_lds[64][136];   // 16B-aligned rows
  __shared__ float row_m[64], row_l[64], row_alpha[64];

  const int t    = threadIdx.x;
  const int id   = blockIdx.x;
  const int xcd  = id & 7;                    // presumed HW XCD of this block
  const int n    = xcd >> 1;                  // pin each image to 2 XCDs
  const int s0   = ((id >> 3) * 2 + (xcd & 1)) * 64;  // bijective: 64 tiles/n
  const int w    = t >> 6;      // 0..7
  const int lane = t & 63;
  const int q    = lane >> 4;
  const int mr   = lane & 15;

  if (t < 64) { row_m[t] = -INFINITY; row_l[t] = 0.f; }

  // Q fragments (64 rows x 128 e) in registers for the whole loop
  bfrag qa[4][4];
  #pragma unroll
  for (int ms = 0; ms < 4; ++ms) {
    const bfrag* rp = reinterpret_cast<const bfrag*>(
        Qt + ((size_t)n * SS + s0 + ms * 16 + mr) * EE);
    #pragma unroll
    for (int k = 0; k < 4; ++k) qa[ms][k] = rp[k * 4 + q];
  }

  f32x4 o_acc[4][2];
  #pragma unroll
  for (int ms = 0; ms < 4; ++ms)
    #pragma unroll
    for (int nt = 0; nt < 2; ++nt) o_acc[ms][nt] = (f32x4){0.f, 0.f, 0.f, 0.f};

  // K fragments for iter 0 (wave w -> key col block w)
  bfrag kb[4];
  {
    const bfrag* rp = reinterpret_cast<const bfrag*>(
        Kt + ((size_t)n * SS + w * 16 + mr) * EE);
    #pragma unroll
    for (int k = 0; k < 4; ++k) kb[k] = rp[k * 4 + q];
  }

  for (int t0 = 0; t0 < SS; t0 += 128) {
    // ---- prefetch V fragments for THIS iter (consumed after softmax) ----
    bfrag vb[4][2];
    #pragma unroll
    for (int nt = 0; nt < 2; ++nt) {
      const int c = w * 32 + nt * 16 + mr;
      const bfrag* vp = reinterpret_cast<const bfrag*>(
          xb + ((size_t)n * CH + c) * SS + t0);
      #pragma unroll
      for (int kk = 0; kk < 4; ++kk) vb[kk][nt] = vp[kk * 4 + q];
    }

    // ---- QK^T: wave w -> 16 key cols ----
    #pragma unroll
    for (int ms = 0; ms < 4; ++ms) {
      f32x4 acc = {0.f, 0.f, 0.f, 0.f};
      #pragma unroll
      for (int k = 0; k < 4; ++k)
        acc = __builtin_amdgcn_mfma_f32_16x16x32_bf16(qa[ms][k], kb[k], acc, 0, 0, 0);
      #pragma unroll
      for (int i = 0; i < 4; ++i)
        S_lds[ms * 16 + q * 4 + i][w * 16 + mr] = acc[i];
    }
    __syncthreads();

    // ---- prefetch K fragments for NEXT iter ----
    {
      const int t1 = t0 + 128;
      if (t1 < SS) {
        const bfrag* rp = reinterpret_cast<const bfrag*>(
            Kt + ((size_t)n * SS + t1 + w * 16 + mr) * EE);
        #pragma unroll
        for (int k = 0; k < 4; ++k) kb[k] = rp[k * 4 + q];
      }
    }

    // ---- online softmax: 8 lanes/row, float4 reads, ushort8 P writes ----
    {
      const int r  = t >> 3;
      const int cg = t & 7;
      const float4* srow = reinterpret_cast<const float4*>(&S_lds[r][cg * 16]);
      float4 v0 = srow[0], v1 = srow[1], v2 = srow[2], v3 = srow[3];
      float vmax = fmaxf(fmaxf(fmaxf(v0.x, v0.y), fmaxf(v0.z, v0.w)),
                         fmaxf(fmaxf(v1.x, v1.y), fmaxf(v1.z, v1.w)));
      vmax = fmaxf(vmax, fmaxf(fmaxf(fmaxf(v2.x, v2.y), fmaxf(v2.z, v2.w)),
                               fmaxf(fmaxf(v3.x, v3.y), fmaxf(v3.z, v3.w))));
      vmax = fmaxf(vmax, __shfl_xor(vmax, 1, 8));
      vmax = fmaxf(vmax, __shfl_xor(vmax, 2, 8));
      vmax = fmaxf(vmax, __shfl_xor(vmax, 4, 8));
      const float m_old = row_m[r];
      const float m_new = fmaxf(m_old, vmax);

      float p[16];
      p[0]=__expf(v0.x-m_new); p[1]=__expf(v0.y-m_new); p[2]=__expf(v0.z-m_new); p[3]=__expf(v0.w-m_new);
      p[4]=__expf(v1.x-m_new); p[5]=__expf(v1.y-m_new); p[6]=__expf(v1.z-m_new); p[7]=__expf(v1.w-m_new);
      p[8]=__expf(v2.x-m_new); p[9]=__expf(v2.y-m_new); p[10]=__expf(v2.z-m_new); p[11]=__expf(v2.w-m_new);
      p[12]=__expf(v3.x-m_new); p[13]=__expf(v3.y-m_new); p[14]=__expf(v3.z-m_new); p[15]=__expf(v3.w-m_new);
      float sum = 0.f;
      u16x8 pk0, pk1;
      #pragma unroll
      for (int j = 0; j < 8; ++j) { sum += p[j];     pk0[j] = f2bf(p[j]); }
      #pragma unroll
      for (int j = 0; j < 8; ++j) { sum += p[8 + j]; pk1[j] = f2bf(p[8 + j]); }
      *reinterpret_cast<u16x8*>(&P_lds[r][cg * 16])     = pk0;
      *reinterpret_cast<u16x8*>(&P_lds[r][cg * 16 + 8]) = pk1;
      sum += __shfl_xor(sum, 1, 8);
      sum += __shfl_xor(sum, 2, 8);
      sum += __shfl_xor(sum, 4, 8);
      if (cg == 0) {
        const float al = __expf(m_old - m_new);   // exp(-inf)=0 on iter 0
        row_alpha[r] = al;
        row_m[r]     = m_new;
        row_l[r]     = row_l[r] * al + sum;
      }
    }
    __syncthreads();

    // ---- rescale O, then O += P @ V ----
    #pragma unroll
    for (int ms = 0; ms < 4; ++ms) {
      float al[4];
      #pragma unroll
      for (int i = 0; i < 4; ++i) al[i] = row_alpha[ms * 16 + q * 4 + i];
      #pragma unroll
      for (int nt = 0; nt < 2; ++nt)
        #pragma unroll
        for (int i = 0; i < 4; ++i) o_acc[ms][nt][i] *= al[i];
    }

    #pragma unroll
    for (int kk = 0; kk < 4; ++kk) {
      bfrag pa[4];
      #pragma unroll
      for (int ms = 0; ms < 4; ++ms)
        pa[ms] = reinterpret_cast<const bfrag*>(&P_lds[ms * 16 + mr][0])[kk * 4 + q];
      #pragma unroll
      for (int nt = 0; nt < 2; ++nt)
        #pragma unroll
        for (int ms = 0; ms < 4; ++ms)
          o_acc[ms][nt] = __builtin_amdgcn_mfma_f32_16x16x32_bf16(
              pa[ms], vb[kk][nt], o_acc[ms][nt], 0, 0, 0);
    }
  }

  // ---- epilogue ----
  #pragma unroll
  for (int ms = 0; ms < 4; ++ms) {
    float inv[4];
    #pragma unroll
    for (int i = 0; i < 4; ++i) inv[i] = 1.0f / row_l[ms * 16 + q * 4 + i];
    #pragma unroll
    for (int nt = 0; nt < 2; ++nt) {
      const int c = w * 32 + nt * 16 + mr;
      #pragma unroll
      for (int i = 0; i < 4; ++i) {
        const int s = s0 + ms * 16 + q * 4 + i;
        Yt[((size_t)n * SS + s) * CH + c] = f2bf(o_acc[ms][nt][i] * inv[i]);
      }
    }
  }
}

// ---------------------------------------------------------------------------
// Pass 3: out[n][o][s] = x[n][o][s] + sum_c proj_w[o][c] * Yt[n][s][c]
// ---------------------------------------------------------------------------
__global__ __launch_bounds__(256) void pass3_proj(
    const unsigned short* __restrict__ Yt,
    const unsigned short* __restrict__ pw,
    const float* __restrict__ x,
    float* __restrict__ out)
{
  const int t    = threadIdx.x;
  const int w    = t >> 6;
  const int lane = t & 63;
  const int q    = lane >> 4;
  const int mr   = lane & 15;
  const int n    = blockIdx.z;
  const int o0   = blockIdx.y * 64 + w * 16;
  const int s1   = blockIdx.x * 64;

  bfrag a[8];
  {
    const bfrag* ap = reinterpret_cast<const bfrag*>(pw + (o0 + mr) * CH);
    #pragma unroll
    for (int k = 0; k < 8; ++k) a[k] = ap[k * 4 + q];
  }

  #pragma unroll
  for (int nt = 0; nt < 4; ++nt) {
    f32x4 acc = {0.f, 0.f, 0.f, 0.f};
    const bfrag* bp = reinterpret_cast<const bfrag*>(
        Yt + ((size_t)n * SS + s1 + nt * 16 + mr) * CH);
    #pragma unroll
    for (int k = 0; k < 8; ++k)
      acc = __builtin_amdgcn_mfma_f32_16x16x32_bf16(a[k], bp[k * 4 + q], acc, 0, 0, 0);
    #pragma unroll
    for (int i = 0; i < 4; ++i) {
      const int o = o0 + q * 4 + i;
      const int s = s1 + nt * 16 + mr;
      const size_t idx = ((size_t)n * CH + o) * SS + s;
      out[idx] = x[idx] + acc[i];
    }
  }
}

// ---------------------------------------------------------------------------
extern "C" void kernel_launch(void* const* d_in, const int* in_sizes, int n_in,
                              void* d_out, int out_size, void* d_ws, size_t ws_size,
                              hipStream_t stream) {
  const float* x   = (const float*)d_in[0];
  const float* thw = (const float*)d_in[1];
  const float* phw = (const float*)d_in[2];
  const float* pw  = (const float*)d_in[3];
  float* out = (float*)d_out;

  unsigned short* xb   = (unsigned short*)d_ws;               // 8 MB
  unsigned short* Yt   = xb + (size_t)NB * CH * SS;           // 8 MB
  unsigned short* Qt   = Yt + (size_t)NB * CH * SS;           // 4 MB
  unsigned short* Kt   = Qt + (size_t)NB * SS * EE;           // 4 MB
  unsigned short* thwb = Kt + (size_t)NB * SS * EE;           // 64 KB
  unsigned short* phwb = thwb + EE * CH;                      // 64 KB
  unsigned short* pwb  = phwb + EE * CH;                      // 128 KB

  const int nx4 = NB * CH * SS / 4;
  const int nw4 = EE * CH / 4;
  const int np4 = CH * CH / 4;
  const int tot4 = nx4 + 2 * nw4 + np4;
  cvt_all<<<(tot4 + 255) / 256, 256, 0, stream>>>(
      x, thw, phw, pw, xb, thwb, phwb, pwb);

  pass1_qk  <<<dim3(SS / 64, NB, 2),       256, 0, stream>>>(xb, thwb, phwb, Qt, Kt);
  pass2_attn<<<dim3(NB * SS / 64),         512, 0, stream>>>(Qt, Kt, xb, Yt);
  pass3_proj<<<dim3(SS / 64, CH / 64, NB), 256, 0, stream>>>(Yt, pwb, x, out);
}

// Round 3
// 196.363 us; speedup vs baseline: 1.6397x; 1.0886x over previous
//
#include <hip/hip_runtime.h>
#include <cstdint>
#include <cstddef>

#define NB 4
#define CH 256
#define SS 4096
#define EE 128
#define QSCALE 0.08838834764831845f /* 1/sqrt(128) */

typedef __attribute__((ext_vector_type(8))) short bfrag;          // 8 bf16 = 4 VGPR
typedef __attribute__((ext_vector_type(8))) unsigned short u16x8; // 16B store
typedef __attribute__((ext_vector_type(4))) float f32x4;          // MFMA acc

__device__ __forceinline__ unsigned short f2bf(float f) {
  union { float f; unsigned int u; } v; v.f = f;
  unsigned int u = v.u;
  unsigned int r = u + 0x7FFFu + ((u >> 16) & 1u);  // RNE
  return (unsigned short)(r >> 16);
}

// ---------------------------------------------------------------------------
// Pass 0: weights-only fp32 -> bf16 (x conversion is fused into pass1 now)
// ---------------------------------------------------------------------------
__global__ __launch_bounds__(256) void cvt_w(
    const float* __restrict__ thw, const float* __restrict__ phw,
    const float* __restrict__ pw,
    unsigned short* __restrict__ thwb, unsigned short* __restrict__ phwb,
    unsigned short* __restrict__ pwb)
{
  const int nw4 = EE * CH / 4;   // 8192
  const int np4 = CH * CH / 4;   // 16384
  int i = blockIdx.x * 256 + threadIdx.x;
  const float* src; unsigned short* dst; int off;
  if      (i < nw4)           { src = thw; dst = thwb; off = i; }
  else if (i < 2 * nw4)       { src = phw; dst = phwb; off = i - nw4; }
  else if (i < 2 * nw4 + np4) { src = pw;  dst = pwb;  off = i - 2 * nw4; }
  else return;
  float4 v = reinterpret_cast<const float4*>(src)[off];
  ushort4 o;
  o.x = f2bf(v.x); o.y = f2bf(v.y); o.z = f2bf(v.z); o.w = f2bf(v.w);
  reinterpret_cast<ushort4*>(dst)[off] = o;
}

// ---------------------------------------------------------------------------
// Pass 1 (fused): per (n, s-tile) block of 512 threads:
//   - load x tile [256 c][64 s] as fp32, convert to bf16 in-register
//   - write xb (bf16 x, byproduct for pass2's V) with coalesced 8B stores
//   - stage transposed xT[s][c] in LDS (staged ONCE, shared by both halves)
//   - waves 0-3: Qt[n][s][e] = QSCALE * theta_w @ x ; waves 4-7: Kt = phi_w @ x
// Grid (SS/64, NB) = 256 blocks.
// ---------------------------------------------------------------------------
__global__ __launch_bounds__(512) void pass1_qk(
    const float* __restrict__ x,
    const unsigned short* __restrict__ thw,
    const unsigned short* __restrict__ phw,
    unsigned short* __restrict__ xb,
    unsigned short* __restrict__ Qt,
    unsigned short* __restrict__ Kt)
{
  __shared__ unsigned short xT[64][CH + 8];
  const int t  = threadIdx.x;
  const int n  = blockIdx.y;
  const int s0 = blockIdx.x * 64;

  // stage: fp32 reads along s (coalesced), cvt, xb write, transposed LDS write
  {
    const int soff = (t & 15) * 4;
    const int c0   = t >> 4;           // 0..31
    #pragma unroll
    for (int ci = 0; ci < 8; ++ci) {
      const int c = c0 + ci * 32;
      const size_t rowoff = ((size_t)n * CH + c) * SS + s0;
      float4 v = reinterpret_cast<const float4*>(x + rowoff)[soff >> 2];
      ushort4 o;
      o.x = f2bf(v.x); o.y = f2bf(v.y); o.z = f2bf(v.z); o.w = f2bf(v.w);
      reinterpret_cast<ushort4*>(xb + rowoff)[soff >> 2] = o;
      xT[soff + 0][c] = o.x;
      xT[soff + 1][c] = o.y;
      xT[soff + 2][c] = o.z;
      xT[soff + 3][c] = o.w;
    }
  }
  __syncthreads();

  const int w    = t >> 6;        // 0..7
  const int lane = t & 63;
  const int q    = lane >> 4;
  const int mr   = lane & 15;
  const int wrow = (w & 3) * 16;  // s-rows within tile
  const int half = w >> 2;        // 0: theta->Qt, 1: phi->Kt

  bfrag a[8];
  {
    const bfrag* rp = reinterpret_cast<const bfrag*>(&xT[wrow + mr][0]);
    #pragma unroll
    for (int k = 0; k < 8; ++k) a[k] = rp[k * 4 + q];
  }

  const unsigned short* wsel = half ? phw : thw;
  unsigned short*       osel = half ? Kt  : Qt;
  const float           sc   = half ? 1.0f : QSCALE;
  const bfrag* wp = reinterpret_cast<const bfrag*>(wsel);
  #pragma unroll
  for (int nt = 0; nt < 8; ++nt) {
    f32x4 acc = {0.f, 0.f, 0.f, 0.f};
    #pragma unroll
    for (int k = 0; k < 8; ++k) {
      bfrag b = wp[(nt * 16 + mr) * (CH / 8) + k * 4 + q];
      acc = __builtin_amdgcn_mfma_f32_16x16x32_bf16(a[k], b, acc, 0, 0, 0);
    }
    #pragma unroll
    for (int i = 0; i < 4; ++i) {
      const int srow = s0 + wrow + q * 4 + i;
      osel[((size_t)n * SS + srow) * EE + nt * 16 + mr] = f2bf(acc[i] * sc);
    }
  }
}

// ---------------------------------------------------------------------------
// Pass 2 (fused): flash attention + projection + residual.
// K/V loop identical to the round-2 kernel (105 us measured). Epilogue writes
// the normalized Y tile [64 s][256 c] to LDS (aliasing the S/P buffers) and
// each wave computes out[o][s] = x + sum_c pw[o][c]*Y[s][c] for its 32 o-rows
// via 64 extra MFMA. Eliminates Yt round-trip (16 MB) and the pass3 launch.
// XCD swizzle: n = (id&7)>>1 pins each image to 2 XCDs (round-2 verified:
// FETCH 51->14 MB).
// ---------------------------------------------------------------------------
__global__ __launch_bounds__(512, 2) void pass2_attn(
    const unsigned short* __restrict__ Qt,
    const unsigned short* __restrict__ Kt,
    const unsigned short* __restrict__ xb,
    const unsigned short* __restrict__ pwb,
    const float* __restrict__ x,
    float* __restrict__ out)
{
  // manual shared-memory layout so the epilogue can reuse the S/P space:
  //   [0      .. 33792)  S_lds  float[64][132]   | epilogue: Y_lds u16[64][264]
  //   [33792  .. 51200)  P_lds  u16[64][136]
  //   [51200  .. 51456)  row_m  float[64]
  //   [51456  .. 51712)  row_l  float[64]
  //   [51712  .. 51968)  row_alpha float[64]
  __shared__ __align__(16) unsigned char SMEM[51968];
  float          (*S_lds)[132] = reinterpret_cast<float(*)[132]>(SMEM);
  unsigned short (*P_lds)[136] = reinterpret_cast<unsigned short(*)[136]>(SMEM + 33792);
  float* row_m     = reinterpret_cast<float*>(SMEM + 51200);
  float* row_l     = reinterpret_cast<float*>(SMEM + 51456);
  float* row_alpha = reinterpret_cast<float*>(SMEM + 51712);

  const int t    = threadIdx.x;
  const int id   = blockIdx.x;
  const int xcd  = id & 7;                    // presumed HW XCD of this block
  const int n    = xcd >> 1;                  // pin each image to 2 XCDs
  const int s0   = ((id >> 3) * 2 + (xcd & 1)) * 64;  // bijective: 64 tiles/n
  const int w    = t >> 6;      // 0..7
  const int lane = t & 63;
  const int q    = lane >> 4;
  const int mr   = lane & 15;

  if (t < 64) { row_m[t] = -INFINITY; row_l[t] = 0.f; }

  // Q fragments (64 rows x 128 e) in registers for the whole loop
  bfrag qa[4][4];
  #pragma unroll
  for (int ms = 0; ms < 4; ++ms) {
    const bfrag* rp = reinterpret_cast<const bfrag*>(
        Qt + ((size_t)n * SS + s0 + ms * 16 + mr) * EE);
    #pragma unroll
    for (int k = 0; k < 4; ++k) qa[ms][k] = rp[k * 4 + q];
  }

  f32x4 o_acc[4][2];
  #pragma unroll
  for (int ms = 0; ms < 4; ++ms)
    #pragma unroll
    for (int nt = 0; nt < 2; ++nt) o_acc[ms][nt] = (f32x4){0.f, 0.f, 0.f, 0.f};

  // K fragments for iter 0 (wave w -> key col block w)
  bfrag kb[4];
  {
    const bfrag* rp = reinterpret_cast<const bfrag*>(
        Kt + ((size_t)n * SS + w * 16 + mr) * EE);
    #pragma unroll
    for (int k = 0; k < 4; ++k) kb[k] = rp[k * 4 + q];
  }

  for (int t0 = 0; t0 < SS; t0 += 128) {
    // ---- prefetch V fragments for THIS iter (consumed after softmax) ----
    bfrag vb[4][2];
    #pragma unroll
    for (int nt = 0; nt < 2; ++nt) {
      const int c = w * 32 + nt * 16 + mr;
      const bfrag* vp = reinterpret_cast<const bfrag*>(
          xb + ((size_t)n * CH + c) * SS + t0);
      #pragma unroll
      for (int kk = 0; kk < 4; ++kk) vb[kk][nt] = vp[kk * 4 + q];
    }

    // ---- QK^T: wave w -> 16 key cols ----
    #pragma unroll
    for (int ms = 0; ms < 4; ++ms) {
      f32x4 acc = {0.f, 0.f, 0.f, 0.f};
      #pragma unroll
      for (int k = 0; k < 4; ++k)
        acc = __builtin_amdgcn_mfma_f32_16x16x32_bf16(qa[ms][k], kb[k], acc, 0, 0, 0);
      #pragma unroll
      for (int i = 0; i < 4; ++i)
        S_lds[ms * 16 + q * 4 + i][w * 16 + mr] = acc[i];
    }
    __syncthreads();

    // ---- prefetch K fragments for NEXT iter ----
    {
      const int t1 = t0 + 128;
      if (t1 < SS) {
        const bfrag* rp = reinterpret_cast<const bfrag*>(
            Kt + ((size_t)n * SS + t1 + w * 16 + mr) * EE);
        #pragma unroll
        for (int k = 0; k < 4; ++k) kb[k] = rp[k * 4 + q];
      }
    }

    // ---- online softmax: 8 lanes/row, float4 reads, ushort8 P writes ----
    {
      const int r  = t >> 3;
      const int cg = t & 7;
      const float4* srow = reinterpret_cast<const float4*>(&S_lds[r][cg * 16]);
      float4 v0 = srow[0], v1 = srow[1], v2 = srow[2], v3 = srow[3];
      float vmax = fmaxf(fmaxf(fmaxf(v0.x, v0.y), fmaxf(v0.z, v0.w)),
                         fmaxf(fmaxf(v1.x, v1.y), fmaxf(v1.z, v1.w)));
      vmax = fmaxf(vmax, fmaxf(fmaxf(fmaxf(v2.x, v2.y), fmaxf(v2.z, v2.w)),
                               fmaxf(fmaxf(v3.x, v3.y), fmaxf(v3.z, v3.w))));
      vmax = fmaxf(vmax, __shfl_xor(vmax, 1, 8));
      vmax = fmaxf(vmax, __shfl_xor(vmax, 2, 8));
      vmax = fmaxf(vmax, __shfl_xor(vmax, 4, 8));
      const float m_old = row_m[r];
      const float m_new = fmaxf(m_old, vmax);

      float p[16];
      p[0]=__expf(v0.x-m_new); p[1]=__expf(v0.y-m_new); p[2]=__expf(v0.z-m_new); p[3]=__expf(v0.w-m_new);
      p[4]=__expf(v1.x-m_new); p[5]=__expf(v1.y-m_new); p[6]=__expf(v1.z-m_new); p[7]=__expf(v1.w-m_new);
      p[8]=__expf(v2.x-m_new); p[9]=__expf(v2.y-m_new); p[10]=__expf(v2.z-m_new); p[11]=__expf(v2.w-m_new);
      p[12]=__expf(v3.x-m_new); p[13]=__expf(v3.y-m_new); p[14]=__expf(v3.z-m_new); p[15]=__expf(v3.w-m_new);
      float sum = 0.f;
      u16x8 pk0, pk1;
      #pragma unroll
      for (int j = 0; j < 8; ++j) { sum += p[j];     pk0[j] = f2bf(p[j]); }
      #pragma unroll
      for (int j = 0; j < 8; ++j) { sum += p[8 + j]; pk1[j] = f2bf(p[8 + j]); }
      *reinterpret_cast<u16x8*>(&P_lds[r][cg * 16])     = pk0;
      *reinterpret_cast<u16x8*>(&P_lds[r][cg * 16 + 8]) = pk1;
      sum += __shfl_xor(sum, 1, 8);
      sum += __shfl_xor(sum, 2, 8);
      sum += __shfl_xor(sum, 4, 8);
      if (cg == 0) {
        const float al = __expf(m_old - m_new);   // exp(-inf)=0 on iter 0
        row_alpha[r] = al;
        row_m[r]     = m_new;
        row_l[r]     = row_l[r] * al + sum;
      }
    }
    __syncthreads();

    // ---- rescale O, then O += P @ V ----
    #pragma unroll
    for (int ms = 0; ms < 4; ++ms) {
      float al[4];
      #pragma unroll
      for (int i = 0; i < 4; ++i) al[i] = row_alpha[ms * 16 + q * 4 + i];
      #pragma unroll
      for (int nt = 0; nt < 2; ++nt)
        #pragma unroll
        for (int i = 0; i < 4; ++i) o_acc[ms][nt][i] *= al[i];
    }

    #pragma unroll
    for (int kk = 0; kk < 4; ++kk) {
      bfrag pa[4];
      #pragma unroll
      for (int ms = 0; ms < 4; ++ms)
        pa[ms] = reinterpret_cast<const bfrag*>(&P_lds[ms * 16 + mr][0])[kk * 4 + q];
      #pragma unroll
      for (int nt = 0; nt < 2; ++nt)
        #pragma unroll
        for (int ms = 0; ms < 4; ++ms)
          o_acc[ms][nt] = __builtin_amdgcn_mfma_f32_16x16x32_bf16(
              pa[ms], vb[kk][nt], o_acc[ms][nt], 0, 0, 0);
    }
  }

  // ---- fused epilogue: Y -> LDS, then out = x + pw @ Y^T ----
  __syncthreads();   // everyone done with S_lds/P_lds of the last iteration
  unsigned short (*Y_lds)[CH + 8] =
      reinterpret_cast<unsigned short(*)[CH + 8]>(SMEM);  // 64*264*2 = 33792 B

  #pragma unroll
  for (int ms = 0; ms < 4; ++ms) {
    float inv[4];
    #pragma unroll
    for (int i = 0; i < 4; ++i) inv[i] = 1.0f / row_l[ms * 16 + q * 4 + i];
    #pragma unroll
    for (int nt = 0; nt < 2; ++nt) {
      const int c = w * 32 + nt * 16 + mr;
      #pragma unroll
      for (int i = 0; i < 4; ++i)
        Y_lds[ms * 16 + q * 4 + i][c] = f2bf(o_acc[ms][nt][i] * inv[i]);
    }
  }
  __syncthreads();

  // projection: wave w computes output rows o = w*32 .. w*32+31
  #pragma unroll
  for (int ot = 0; ot < 2; ++ot) {
    const int o0 = w * 32 + ot * 16;
    bfrag a[8];
    {
      const bfrag* ap = reinterpret_cast<const bfrag*>(pwb + (o0 + mr) * CH);
      #pragma unroll
      for (int k = 0; k < 8; ++k) a[k] = ap[k * 4 + q];
    }
    #pragma unroll
    for (int st = 0; st < 4; ++st) {
      f32x4 acc = {0.f, 0.f, 0.f, 0.f};
      const bfrag* bp = reinterpret_cast<const bfrag*>(&Y_lds[st * 16 + mr][0]);
      #pragma unroll
      for (int k = 0; k < 8; ++k)
        acc = __builtin_amdgcn_mfma_f32_16x16x32_bf16(a[k], bp[k * 4 + q], acc, 0, 0, 0);
      #pragma unroll
      for (int i = 0; i < 4; ++i) {
        const int o = o0 + q * 4 + i;
        const int s = s0 + st * 16 + mr;
        const size_t idx = ((size_t)n * CH + o) * SS + s;
        out[idx] = x[idx] + acc[i];
      }
    }
  }
}

// ---------------------------------------------------------------------------
extern "C" void kernel_launch(void* const* d_in, const int* in_sizes, int n_in,
                              void* d_out, int out_size, void* d_ws, size_t ws_size,
                              hipStream_t stream) {
  const float* x   = (const float*)d_in[0];
  const float* thw = (const float*)d_in[1];
  const float* phw = (const float*)d_in[2];
  const float* pw  = (const float*)d_in[3];
  float* out = (float*)d_out;

  unsigned short* xb   = (unsigned short*)d_ws;               // 8 MB
  unsigned short* Qt   = xb + (size_t)NB * CH * SS;           // 4 MB
  unsigned short* Kt   = Qt + (size_t)NB * SS * EE;           // 4 MB
  unsigned short* thwb = Kt + (size_t)NB * SS * EE;           // 64 KB
  unsigned short* phwb = thwb + EE * CH;                      // 64 KB
  unsigned short* pwb  = phwb + EE * CH;                      // 128 KB

  const int nw4 = EE * CH / 4;
  const int np4 = CH * CH / 4;
  const int totw4 = 2 * nw4 + np4;
  cvt_w<<<(totw4 + 255) / 256, 256, 0, stream>>>(thw, phw, pw, thwb, phwb, pwb);

  pass1_qk  <<<dim3(SS / 64, NB), 512, 0, stream>>>(x, thwb, phwb, xb, Qt, Kt);
  pass2_attn<<<dim3(NB * SS / 64), 512, 0, stream>>>(Qt, Kt, xb, pwb, x, out);
}